// Round 1
// baseline (2108.309 us; speedup 1.0000x reference)
//
#include <hip/hip_runtime.h>
#include <cmath>

#define Bn 8
#define Ln 4096
#define Dn 256
#define NEGV (-1e30f)

// ws layout (float offsets)
#define OFF_Q    0ul          // 8*4096*256 floats; later reused as attn
#define OFF_K    8388608ul    // later reused as t
#define OFF_V    16777216ul
#define OFF_LENS 25165824ul   // 8 ints
#define OFF_SUMS 25165888ul   // sums[0..255]=sum(t), sums[256..511]=sum(t^2)

__global__ __launch_bounds__(256) void k_init(const int* __restrict__ mask, int* __restrict__ lens,
                                              float* __restrict__ sums) {
  const int b = blockIdx.x, tid = threadIdx.x;
  if (b == 0) { sums[tid] = 0.f; sums[256 + tid] = 0.f; }
  int cnt = 0;
  for (int l = tid; l < Ln; l += 256) cnt += (mask[b * Ln + l] != 0) ? 1 : 0;
  __shared__ int red[256];
  red[tid] = cnt;
  __syncthreads();
  for (int s = 128; s > 0; s >>= 1) {
    if (tid < s) red[tid] += red[tid + s];
    __syncthreads();
  }
  if (tid == 0) lens[b] = red[0];
}

// C[M,256] = A[M,256] @ W[256,256], row-major. 64x64 tile per block, 4x4 micro.
__global__ __launch_bounds__(256) void k_gemm(const float* __restrict__ A, const float* __restrict__ W,
                                              float* __restrict__ C) {
  __shared__ float As[16][68];  // transposed: As[k][row]
  __shared__ float Ws[16][68];  // Ws[k][col]
  const int tid = threadIdx.x;
  const size_t row0 = (size_t)blockIdx.x * 64;
  const int col0 = blockIdx.y * 64;
  const int r0 = (tid >> 4) * 4;
  const int c0 = (tid & 15) * 4;
  float4 acc[4];
  acc[0] = acc[1] = acc[2] = acc[3] = make_float4(0.f, 0.f, 0.f, 0.f);
  for (int kk = 0; kk < 256; kk += 16) {
    __syncthreads();
#pragma unroll
    for (int i = 0; i < 4; ++i) {
      int flat = tid + i * 256;
      int r = flat >> 4, c = flat & 15;
      As[c][r] = A[(row0 + r) * Dn + kk + c];
      int k2 = flat >> 6, c2 = flat & 63;
      Ws[k2][c2] = W[(size_t)(kk + k2) * Dn + col0 + c2];
    }
    __syncthreads();
#pragma unroll
    for (int k3 = 0; k3 < 16; ++k3) {
      float4 a = *(const float4*)&As[k3][r0];
      float4 b = *(const float4*)&Ws[k3][c0];
      acc[0].x += a.x * b.x; acc[0].y += a.x * b.y; acc[0].z += a.x * b.z; acc[0].w += a.x * b.w;
      acc[1].x += a.y * b.x; acc[1].y += a.y * b.y; acc[1].z += a.y * b.z; acc[1].w += a.y * b.w;
      acc[2].x += a.z * b.x; acc[2].y += a.z * b.y; acc[2].z += a.z * b.z; acc[2].w += a.z * b.w;
      acc[3].x += a.w * b.x; acc[3].y += a.w * b.y; acc[3].z += a.w * b.z; acc[3].w += a.w * b.w;
    }
  }
#pragma unroll
  for (int i = 0; i < 4; ++i)
    *(float4*)&C[(row0 + r0 + i) * Dn + col0 + c0] = acc[i];
}

// Flash attention (fp32): 32 queries/block, key tiles of 32, online softmax.
// attn may alias q: block reads its q rows into LDS before writing attn rows.
__global__ __launch_bounds__(256) void k_flash(const float* __restrict__ qg, const float* __restrict__ kg,
                                               const float* __restrict__ vg, const int* __restrict__ lens,
                                               float* __restrict__ attn) {
  const int b = blockIdx.y;
  const int len = lens[b];
  const int i0 = blockIdx.x * 32;
  if (i0 >= len) return;
  const int tid = threadIdx.x;
  const int rp = tid >> 4;  // 0..15 -> rows 2rp, 2rp+1
  const int jp = tid & 15;  // 0..15 -> keys jp, jp+16 ; PV channels 4jp+64c
  __shared__ float qs[32][268];
  __shared__ float ks[32][268];  // k tile, then reused as v tile
  __shared__ float Ps[32][33];
  const float* qb = qg + (size_t)b * Ln * Dn;
  const float* kb = kg + (size_t)b * Ln * Dn;
  const float* vb = vg + (size_t)b * Ln * Dn;
#pragma unroll
  for (int i = 0; i < 8; ++i) {
    int flat = tid + i * 256;
    int r = flat >> 6, c = (flat & 63) * 4;
    *(float4*)&qs[r][c] = *(const float4*)&qb[(size_t)(i0 + r) * Dn + c];
  }
  const int r0 = 2 * rp, r1 = 2 * rp + 1;
  float m0 = -INFINITY, m1 = -INFINITY, l0 = 0.f, l1 = 0.f;
  float4 o0[4], o1[4];
#pragma unroll
  for (int c = 0; c < 4; ++c) { o0[c] = make_float4(0,0,0,0); o1[c] = make_float4(0,0,0,0); }

  for (int j0 = 0; j0 < len; j0 += 32) {
    __syncthreads();  // previous PV done with ks; also covers initial qs load
#pragma unroll
    for (int i = 0; i < 8; ++i) {
      int flat = tid + i * 256;
      int r = flat >> 6, c = (flat & 63) * 4;
      *(float4*)&ks[r][c] = *(const float4*)&kb[(size_t)(j0 + r) * Dn + c];
    }
    __syncthreads();
    float s00 = 0.f, s01 = 0.f, s10 = 0.f, s11 = 0.f;
#pragma unroll 4
    for (int d = 0; d < Dn; d += 4) {
      float4 qa = *(const float4*)&qs[r0][d];
      float4 qc = *(const float4*)&qs[r1][d];
      float4 ka = *(const float4*)&ks[jp][d];
      float4 kc = *(const float4*)&ks[jp + 16][d];
      s00 += qa.x * ka.x; s00 += qa.y * ka.y; s00 += qa.z * ka.z; s00 += qa.w * ka.w;
      s01 += qa.x * kc.x; s01 += qa.y * kc.y; s01 += qa.z * kc.z; s01 += qa.w * kc.w;
      s10 += qc.x * ka.x; s10 += qc.y * ka.y; s10 += qc.z * ka.z; s10 += qc.w * ka.w;
      s11 += qc.x * kc.x; s11 += qc.y * kc.y; s11 += qc.z * kc.z; s11 += qc.w * kc.w;
    }
    if (j0 + jp >= len) { s00 = NEGV; s10 = NEGV; }
    if (j0 + jp + 16 >= len) { s01 = NEGV; s11 = NEGV; }
    float rm0 = fmaxf(s00, s01), rm1 = fmaxf(s10, s11);
#pragma unroll
    for (int w = 1; w < 16; w <<= 1) {
      rm0 = fmaxf(rm0, __shfl_xor(rm0, w));
      rm1 = fmaxf(rm1, __shfl_xor(rm1, w));
    }
    float mn0 = fmaxf(m0, rm0), mn1 = fmaxf(m1, rm1);
    float a0 = __expf(m0 - mn0), a1 = __expf(m1 - mn1);
    float p00 = __expf(s00 - mn0), p01 = __expf(s01 - mn0);
    float p10 = __expf(s10 - mn1), p11 = __expf(s11 - mn1);
    float rs0 = p00 + p01, rs1 = p10 + p11;
#pragma unroll
    for (int w = 1; w < 16; w <<= 1) {
      rs0 += __shfl_xor(rs0, w);
      rs1 += __shfl_xor(rs1, w);
    }
    l0 = l0 * a0 + rs0; l1 = l1 * a1 + rs1;
    m0 = mn0; m1 = mn1;
    Ps[r0][jp] = p00; Ps[r0][jp + 16] = p01;
    Ps[r1][jp] = p10; Ps[r1][jp + 16] = p11;
#pragma unroll
    for (int c = 0; c < 4; ++c) {
      o0[c].x *= a0; o0[c].y *= a0; o0[c].z *= a0; o0[c].w *= a0;
      o1[c].x *= a1; o1[c].y *= a1; o1[c].z *= a1; o1[c].w *= a1;
    }
    __syncthreads();  // S-phase ks reads + Ps writes done -> load v over ks
#pragma unroll
    for (int i = 0; i < 8; ++i) {
      int flat = tid + i * 256;
      int r = flat >> 6, c = (flat & 63) * 4;
      *(float4*)&ks[r][c] = *(const float4*)&vb[(size_t)(j0 + r) * Dn + c];
    }
    __syncthreads();
#pragma unroll 4
    for (int j = 0; j < 32; ++j) {
      float pa = Ps[r0][j], pb = Ps[r1][j];
#pragma unroll
      for (int c = 0; c < 4; ++c) {
        float4 vv = *(const float4*)&ks[j][4 * jp + 64 * c];
        o0[c].x += pa * vv.x; o0[c].y += pa * vv.y; o0[c].z += pa * vv.z; o0[c].w += pa * vv.w;
        o1[c].x += pb * vv.x; o1[c].y += pb * vv.y; o1[c].z += pb * vv.z; o1[c].w += pb * vv.w;
      }
    }
  }
  float* ab = attn + (size_t)b * Ln * Dn;
  float inv0 = 1.f / l0, inv1 = 1.f / l1;
  if (i0 + r0 < len) {
#pragma unroll
    for (int c = 0; c < 4; ++c) {
      float4 t = o0[c];
      t.x *= inv0; t.y *= inv0; t.z *= inv0; t.w *= inv0;
      *(float4*)&ab[(size_t)(i0 + r0) * Dn + 4 * jp + 64 * c] = t;
    }
  }
  if (i0 + r1 < len) {
#pragma unroll
    for (int c = 0; c < 4; ++c) {
      float4 t = o1[c];
      t.x *= inv1; t.y *= inv1; t.z *= inv1; t.w *= inv1;
      *(float4*)&ab[(size_t)(i0 + r1) * Dn + 4 * jp + 64 * c] = t;
    }
  }
}

__global__ __launch_bounds__(256) void k_stats(const float* __restrict__ t, const int* __restrict__ mask,
                                               float* __restrict__ sums) {
  const int c = threadIdx.x;
  const int r0 = blockIdx.x * 128;
  float s = 0.f, s2 = 0.f;
  for (int r = r0; r < r0 + 128; ++r) {
    if (mask[r] != 0) {
      float xv = t[(size_t)r * Dn + c];
      s += xv; s2 += xv * xv;
    }
  }
  atomicAdd(&sums[c], s);
  atomicAdd(&sums[256 + c], s2);
}

__device__ __forceinline__ float bn_relu(float tv, int ch, float fn, const float* sums,
                                         const float* gamma, const float* beta) {
  float mean = sums[ch] / fn;
  float var = sums[256 + ch] / fn - mean * mean;
  float y = gamma[ch] * (tv - mean) * rsqrtf(var + 1e-4f) + beta[ch];
  return y > 0.f ? y : 0.f;
}

__global__ __launch_bounds__(256) void k_final(const float* __restrict__ x, const int* __restrict__ mask,
                                               const float* __restrict__ t, const float* __restrict__ gamma,
                                               const float* __restrict__ beta, const float* __restrict__ sums,
                                               const int* __restrict__ lens, float* __restrict__ out) {
  const size_t idx = (size_t)blockIdx.x * 256 + threadIdx.x;  // float4 index
  const size_t row = idx >> 6;
  const int c = (int)(idx & 63) * 4;
  float4 o;
  if (mask[row] == 0) {
    o = make_float4(0.f, 0.f, 0.f, 0.f);
  } else {
    int n = 0;
#pragma unroll
    for (int i = 0; i < 8; ++i) n += lens[i];
    const float fn = (float)n;
    float4 tv = *(const float4*)&t[row * Dn + c];
    float4 xv = *(const float4*)&x[row * Dn + c];
    o.x = xv.x + bn_relu(tv.x, c + 0, fn, sums, gamma, beta);
    o.y = xv.y + bn_relu(tv.y, c + 1, fn, sums, gamma, beta);
    o.z = xv.z + bn_relu(tv.z, c + 2, fn, sums, gamma, beta);
    o.w = xv.w + bn_relu(tv.w, c + 3, fn, sums, gamma, beta);
  }
  *(float4*)&out[idx * 4] = o;
}

extern "C" void kernel_launch(void* const* d_in, const int* in_sizes, int n_in,
                              void* d_out, int out_size, void* d_ws, size_t ws_size,
                              hipStream_t stream) {
  const float* x = (const float*)d_in[0];
  const int* mask = (const int*)d_in[1];
  const float* Wq = (const float*)d_in[2];
  const float* Wk = (const float*)d_in[3];
  const float* Wv = (const float*)d_in[4];
  const float* Wt = (const float*)d_in[5];
  const float* gamma = (const float*)d_in[6];
  const float* beta = (const float*)d_in[7];
  float* out = (float*)d_out;
  float* ws = (float*)d_ws;
  float* q = ws + OFF_Q;
  float* k = ws + OFF_K;
  float* v = ws + OFF_V;
  int* lens = (int*)(ws + OFF_LENS);
  float* sums = ws + OFF_SUMS;

  k_init<<<8, 256, 0, stream>>>(mask, lens, sums);
  k_gemm<<<dim3(512, 4), 256, 0, stream>>>(x, Wq, q);
  k_gemm<<<dim3(512, 4), 256, 0, stream>>>(x, Wk, k);
  k_gemm<<<dim3(512, 4), 256, 0, stream>>>(x, Wv, v);
  k_flash<<<dim3(128, 8), 256, 0, stream>>>(q, k, v, lens, q);  // attn overwrites q (safe)
  k_gemm<<<dim3(512, 4), 256, 0, stream>>>(q, Wt, k);           // t overwrites k (k done)
  k_stats<<<256, 256, 0, stream>>>(k, mask, sums);
  k_final<<<8192, 256, 0, stream>>>(x, mask, k, gamma, beta, sums, lens, out);
}

// Round 2
// 627.168 us; speedup vs baseline: 3.3616x; 3.3616x over previous
//
#include <hip/hip_runtime.h>
#include <cmath>

typedef _Float16 f16;
typedef f16 f16x8 __attribute__((ext_vector_type(8)));
typedef f16 f16x4 __attribute__((ext_vector_type(4)));
typedef float f32x4 __attribute__((ext_vector_type(4)));

#define Ln 4096
#define Dn 256
#define NEGV (-1e30f)

// workspace byte offsets (total 80MB + 3KB; R0 proved >=100.6MB available)
#define B_QH   0ul           // fp16 Q [8][4096][256] = 16MB   (dead after flash)
#define B_KH   (16ul << 20)  // fp16 K [8][4096][256] = 16MB   (dead after flash)
#define B_VT   (32ul << 20)  // fp16 V^T [8][256][4096] = 16MB
#define B_ATT  (48ul << 20)  // fp32 attn [8][4096][256] = 32MB
#define B_T    0ul           // fp32 t [8][4096][256] = 32MB, overlays QH+KH (dead)
#define B_LENS (80ul << 20)

__device__ __forceinline__ void async_ld16(f16* lds, const f16* g) {
  __builtin_amdgcn_global_load_lds((const __attribute__((address_space(1))) unsigned int*)g,
                                   (__attribute__((address_space(3))) unsigned int*)lds, 16, 0, 0);
}

__global__ __launch_bounds__(256) void k_init(const int* __restrict__ mask, int* __restrict__ lens,
                                              float* __restrict__ sums) {
  const int b = blockIdx.x, tid = threadIdx.x;
  if (b == 0) { sums[tid] = 0.f; sums[256 + tid] = 0.f; }
  int cnt = 0;
  for (int l = tid; l < Ln; l += 256) cnt += (mask[b * Ln + l] != 0) ? 1 : 0;
  __shared__ int red[256];
  red[tid] = cnt;
  __syncthreads();
  for (int s = 128; s > 0; s >>= 1) {
    if (tid < s) red[tid] += red[tid + s];
    __syncthreads();
  }
  if (tid == 0) lens[b] = red[0];
}

// fp32 SGEMM 64x64 tile; C fp32 (used for t = attn @ Wt)
__global__ __launch_bounds__(256) void k_gemm(const float* __restrict__ A, const float* __restrict__ W,
                                              float* __restrict__ C) {
  __shared__ float As[16][68];
  __shared__ float Ws[16][68];
  const int tid = threadIdx.x;
  const size_t row0 = (size_t)blockIdx.x * 64;
  const int col0 = blockIdx.y * 64;
  const int r0 = (tid >> 4) * 4;
  const int c0 = (tid & 15) * 4;
  float acc[4][4] = {};
  for (int kk = 0; kk < 256; kk += 16) {
    __syncthreads();
#pragma unroll
    for (int i = 0; i < 4; ++i) {
      int flat = tid + i * 256;
      int r = flat >> 4, c = flat & 15;
      As[c][r] = A[(row0 + r) * Dn + kk + c];
      int k2 = flat >> 6, c2 = flat & 63;
      Ws[k2][c2] = W[(size_t)(kk + k2) * Dn + col0 + c2];
    }
    __syncthreads();
#pragma unroll
    for (int k3 = 0; k3 < 16; ++k3) {
#pragma unroll
      for (int i = 0; i < 4; ++i) {
        float av = As[k3][r0 + i];
#pragma unroll
        for (int j = 0; j < 4; ++j) acc[i][j] += av * Ws[k3][c0 + j];
      }
    }
  }
#pragma unroll
  for (int i = 0; i < 4; ++i) {
    float4 v = make_float4(acc[i][0], acc[i][1], acc[i][2], acc[i][3]);
    *(float4*)&C[(row0 + r0 + i) * Dn + col0 + c0] = v;
  }
}

// fp32 SGEMM, fp16 row-major output (Q, K)
__global__ __launch_bounds__(256) void k_gemm_h(const float* __restrict__ A, const float* __restrict__ W,
                                                f16* __restrict__ C) {
  __shared__ float As[16][68];
  __shared__ float Ws[16][68];
  const int tid = threadIdx.x;
  const size_t row0 = (size_t)blockIdx.x * 64;
  const int col0 = blockIdx.y * 64;
  const int r0 = (tid >> 4) * 4;
  const int c0 = (tid & 15) * 4;
  float acc[4][4] = {};
  for (int kk = 0; kk < 256; kk += 16) {
    __syncthreads();
#pragma unroll
    for (int i = 0; i < 4; ++i) {
      int flat = tid + i * 256;
      int r = flat >> 4, c = flat & 15;
      As[c][r] = A[(row0 + r) * Dn + kk + c];
      int k2 = flat >> 6, c2 = flat & 63;
      Ws[k2][c2] = W[(size_t)(kk + k2) * Dn + col0 + c2];
    }
    __syncthreads();
#pragma unroll
    for (int k3 = 0; k3 < 16; ++k3) {
#pragma unroll
      for (int i = 0; i < 4; ++i) {
        float av = As[k3][r0 + i];
#pragma unroll
        for (int j = 0; j < 4; ++j) acc[i][j] += av * Ws[k3][c0 + j];
      }
    }
  }
#pragma unroll
  for (int i = 0; i < 4; ++i) {
    f16x4 h = {(f16)acc[i][0], (f16)acc[i][1], (f16)acc[i][2], (f16)acc[i][3]};
    *(f16x4*)&C[(row0 + r0 + i) * Dn + col0 + c0] = h;
  }
}

// fp32 SGEMM, fp16 TRANSPOSED output: C[b][col][row%4096] (V^T for the PV B-operand)
__global__ __launch_bounds__(256) void k_gemm_vt(const float* __restrict__ A, const float* __restrict__ W,
                                                 f16* __restrict__ C) {
  __shared__ float As[16][68];
  __shared__ float Ws[16][68];
  const int tid = threadIdx.x;
  const size_t row0 = (size_t)blockIdx.x * 64;
  const int col0 = blockIdx.y * 64;
  const int r0 = (tid >> 4) * 4;
  const int c0 = (tid & 15) * 4;
  float acc[4][4] = {};
  for (int kk = 0; kk < 256; kk += 16) {
    __syncthreads();
#pragma unroll
    for (int i = 0; i < 4; ++i) {
      int flat = tid + i * 256;
      int r = flat >> 4, c = flat & 15;
      As[c][r] = A[(row0 + r) * Dn + kk + c];
      int k2 = flat >> 6, c2 = flat & 63;
      Ws[k2][c2] = W[(size_t)(kk + k2) * Dn + col0 + c2];
    }
    __syncthreads();
#pragma unroll
    for (int k3 = 0; k3 < 16; ++k3) {
#pragma unroll
      for (int i = 0; i < 4; ++i) {
        float av = As[k3][r0 + i];
#pragma unroll
        for (int j = 0; j < 4; ++j) acc[i][j] += av * Ws[k3][c0 + j];
      }
    }
  }
  const int bb = (int)(row0 >> 12);
  const int l0 = (int)(row0 & 4095) + r0;
#pragma unroll
  for (int j = 0; j < 4; ++j) {
    f16x4 h = {(f16)acc[0][j], (f16)acc[1][j], (f16)acc[2][j], (f16)acc[3][j]};
    *(f16x4*)&C[(size_t)bb * Dn * Ln + (size_t)(col0 + c0 + j) * Ln + l0] = h;
  }
}

// MFMA flash attention: 32 queries/block, 64-key tiles, 4 waves.
// S phase: wave (wq,wk) computes S[16q x 32k]; PV: wave (wq,wk) owns O[16q x 128ch].
__global__ __launch_bounds__(256) void k_flash(const f16* __restrict__ Qh, const f16* __restrict__ Kh,
                                               const f16* __restrict__ Vt, const int* __restrict__ lens,
                                               float* __restrict__ attn) {
  const int b = blockIdx.y;
  const int len = lens[b];
  const int i0 = blockIdx.x * 32;
  if (i0 >= len) return;
  const int tid = threadIdx.x;
  const int lane = tid & 63;
  const int ln15 = lane & 15;
  const int quad = lane >> 4;
  const int wave = tid >> 6;
  const int wq = wave >> 1;
  const int wk = wave & 1;

  __shared__ f16 sK[64 * 256];   // row-major keys, 16B-granule XOR-swizzled
  __shared__ f16 sV[256 * 64];   // V^T: [ch][key], swizzled
  __shared__ f16 sP[32 * 80];    // P tile, padded stride
  __shared__ float sRed[2][2][32];

  const f16* Qb = Qh + (size_t)b * Ln * Dn;
  const f16* Kb = Kh + (size_t)b * Ln * Dn;
  const f16* Vb = Vt + (size_t)b * Dn * Ln;
  float* Ab = attn + (size_t)b * Ln * Dn;

  f16x8 qf[8];
  {
    const f16* qrow = Qb + (size_t)(i0 + wq * 16 + ln15) * Dn + quad * 8;
#pragma unroll
    for (int c = 0; c < 8; ++c) qf[c] = *(const f16x8*)(qrow + c * 32);
  }

  f32x4 oAcc[8];
#pragma unroll
  for (int nf = 0; nf < 8; ++nf) { oAcc[nf][0] = 0.f; oAcc[nf][1] = 0.f; oAcc[nf][2] = 0.f; oAcc[nf][3] = 0.f; }
  float m_i[4], l_i[4];
#pragma unroll
  for (int i = 0; i < 4; ++i) { m_i[i] = -INFINITY; l_i[i] = 0.f; }

  for (int j0 = 0; j0 < len; j0 += 64) {
    __syncthreads();  // prev PV done with sK/sV/sP
    {
      const f16* src = Kb + (size_t)j0 * Dn;
#pragma unroll
      for (int i = 0; i < 8; ++i) {
        int flat = i * 256 + tid;
        int r = flat >> 5, p = flat & 31;
        int g = p ^ (r & 7);
        async_ld16(&sK[(i * 256 + (tid & 192)) * 8], src + r * 256 + g * 8);
      }
      const f16* vsrc = Vb + j0;
#pragma unroll
      for (int i = 0; i < 8; ++i) {
        int flat = i * 256 + tid;
        int r = flat >> 3, p = flat & 7;
        int g = p ^ (r & 7);
        async_ld16(&sV[(i * 256 + (tid & 192)) * 8], vsrc + (size_t)r * Ln + g * 8);
      }
    }
    __syncthreads();  // staging visible

    f32x4 s0, s1;
    s0[0] = s0[1] = s0[2] = s0[3] = 0.f;
    s1[0] = s1[1] = s1[2] = s1[3] = 0.f;
    const int kr0 = wk * 32 + ln15;
    const int kr1 = kr0 + 16;
    const int sw = (kr0 & 7);  // same for kr1
#pragma unroll
    for (int c = 0; c < 8; ++c) {
      int g = c * 4 + quad;
      f16x8 b0 = *(const f16x8*)&sK[kr0 * 256 + ((g ^ sw) << 3)];
      f16x8 b1 = *(const f16x8*)&sK[kr1 * 256 + ((g ^ sw) << 3)];
      s0 = __builtin_amdgcn_mfma_f32_16x16x32_f16(qf[c], b0, s0, 0, 0, 0);
      s1 = __builtin_amdgcn_mfma_f32_16x16x32_f16(qf[c], b1, s1, 0, 0, 0);
    }

    const int keyg = j0 + wk * 32 + ln15;
    const bool inv0 = keyg >= len, inv1 = keyg + 16 >= len;
    float rowmax[4], mnew[4], psum[4];
#pragma unroll
    for (int i = 0; i < 4; ++i) {
      float a = inv0 ? NEGV : s0[i];
      float c2 = inv1 ? NEGV : s1[i];
      s0[i] = a; s1[i] = c2;
      float rm = fmaxf(a, c2);
      rm = fmaxf(rm, __shfl_xor(rm, 1));
      rm = fmaxf(rm, __shfl_xor(rm, 2));
      rm = fmaxf(rm, __shfl_xor(rm, 4));
      rm = fmaxf(rm, __shfl_xor(rm, 8));
      rowmax[i] = rm;
    }
    if (ln15 == 0) {
#pragma unroll
      for (int i = 0; i < 4; ++i) sRed[0][wk][wq * 16 + quad * 4 + i] = rowmax[i];
    }
    __syncthreads();
#pragma unroll
    for (int i = 0; i < 4; ++i) {
      int row = wq * 16 + quad * 4 + i;
      float mo = fmaxf(sRed[0][0][row], sRed[0][1][row]);
      float mn = fmaxf(m_i[i], mo);
      mnew[i] = mn;
      float p0 = __expf(s0[i] - mn), p1 = __expf(s1[i] - mn);
      float rs = p0 + p1;
      rs += __shfl_xor(rs, 1);
      rs += __shfl_xor(rs, 2);
      rs += __shfl_xor(rs, 4);
      rs += __shfl_xor(rs, 8);
      psum[i] = rs;
      sP[row * 80 + wk * 32 + ln15] = (f16)p0;
      sP[row * 80 + wk * 32 + 16 + ln15] = (f16)p1;
    }
    if (ln15 == 0) {
#pragma unroll
      for (int i = 0; i < 4; ++i) sRed[1][wk][wq * 16 + quad * 4 + i] = psum[i];
    }
    __syncthreads();
    float alpha[4];
#pragma unroll
    for (int i = 0; i < 4; ++i) {
      int row = wq * 16 + quad * 4 + i;
      float tot = sRed[1][0][row] + sRed[1][1][row];
      float al = __expf(m_i[i] - mnew[i]);
      l_i[i] = l_i[i] * al + tot;
      m_i[i] = mnew[i];
      alpha[i] = al;
    }
#pragma unroll
    for (int nf = 0; nf < 8; ++nf) {
#pragma unroll
      for (int i = 0; i < 4; ++i) oAcc[nf][i] *= alpha[i];
    }
#pragma unroll
    for (int c = 0; c < 2; ++c) {
      f16x8 pa = *(const f16x8*)&sP[(wq * 16 + ln15) * 80 + c * 32 + quad * 8];
#pragma unroll
      for (int nf = 0; nf < 8; ++nf) {
        int ch = wk * 128 + nf * 16 + ln15;
        int g = c * 4 + quad;
        f16x8 vb2 = *(const f16x8*)&sV[ch * 64 + ((g ^ (ch & 7)) << 3)];
        oAcc[nf] = __builtin_amdgcn_mfma_f32_16x16x32_f16(pa, vb2, oAcc[nf], 0, 0, 0);
      }
    }
  }

#pragma unroll
  for (int i = 0; i < 4; ++i) {
    int row = i0 + wq * 16 + quad * 4 + i;
    if (row < len) {
      float inv = 1.f / l_i[i];
#pragma unroll
      for (int nf = 0; nf < 8; ++nf)
        Ab[(size_t)row * Dn + wk * 128 + nf * 16 + ln15] = oAcc[nf][i] * inv;
    }
  }
}

__global__ __launch_bounds__(256) void k_stats(const float* __restrict__ t, const int* __restrict__ mask,
                                               float* __restrict__ sums) {
  const int c = threadIdx.x;
  const int r0 = blockIdx.x * 128;
  float s = 0.f, s2 = 0.f;
  for (int r = r0; r < r0 + 128; ++r) {
    if (mask[r] != 0) {
      float xv = t[(size_t)r * Dn + c];
      s += xv; s2 += xv * xv;
    }
  }
  atomicAdd(&sums[c], s);
  atomicAdd(&sums[256 + c], s2);
}

__device__ __forceinline__ float bn_relu(float tv, int ch, float fn, const float* sums,
                                         const float* gamma, const float* beta) {
  float mean = sums[ch] / fn;
  float var = sums[256 + ch] / fn - mean * mean;
  float y = gamma[ch] * (tv - mean) * rsqrtf(var + 1e-4f) + beta[ch];
  return y > 0.f ? y : 0.f;
}

__global__ __launch_bounds__(256) void k_final(const float* __restrict__ x, const int* __restrict__ mask,
                                               const float* __restrict__ t, const float* __restrict__ gamma,
                                               const float* __restrict__ beta, const float* __restrict__ sums,
                                               const int* __restrict__ lens, float* __restrict__ out) {
  const size_t idx = (size_t)blockIdx.x * 256 + threadIdx.x;  // float4 index
  const size_t row = idx >> 6;
  const int c = (int)(idx & 63) * 4;
  float4 o;
  if (mask[row] == 0) {
    o = make_float4(0.f, 0.f, 0.f, 0.f);
  } else {
    int n = 0;
#pragma unroll
    for (int i = 0; i < 8; ++i) n += lens[i];
    const float fn = (float)n;
    float4 tv = *(const float4*)&t[row * Dn + c];
    float4 xv = *(const float4*)&x[row * Dn + c];
    o.x = xv.x + bn_relu(tv.x, c + 0, fn, sums, gamma, beta);
    o.y = xv.y + bn_relu(tv.y, c + 1, fn, sums, gamma, beta);
    o.z = xv.z + bn_relu(tv.z, c + 2, fn, sums, gamma, beta);
    o.w = xv.w + bn_relu(tv.w, c + 3, fn, sums, gamma, beta);
  }
  *(float4*)&out[idx * 4] = o;
}

extern "C" void kernel_launch(void* const* d_in, const int* in_sizes, int n_in,
                              void* d_out, int out_size, void* d_ws, size_t ws_size,
                              hipStream_t stream) {
  const float* x = (const float*)d_in[0];
  const int* mask = (const int*)d_in[1];
  const float* Wq = (const float*)d_in[2];
  const float* Wk = (const float*)d_in[3];
  const float* Wv = (const float*)d_in[4];
  const float* Wt = (const float*)d_in[5];
  const float* gamma = (const float*)d_in[6];
  const float* beta = (const float*)d_in[7];
  float* out = (float*)d_out;
  char* wsb = (char*)d_ws;

  f16* Qh = (f16*)(wsb + B_QH);
  f16* Kh = (f16*)(wsb + B_KH);
  f16* Vt = (f16*)(wsb + B_VT);
  float* attn = (float*)(wsb + B_ATT);
  float* t = (float*)(wsb + B_T);
  int* lens = (int*)(wsb + B_LENS);
  float* sums = (float*)(wsb + B_LENS + 256);

  k_init<<<8, 256, 0, stream>>>(mask, lens, sums);
  k_gemm_h<<<dim3(512, 4), 256, 0, stream>>>(x, Wq, Qh);
  k_gemm_h<<<dim3(512, 4), 256, 0, stream>>>(x, Wk, Kh);
  k_gemm_vt<<<dim3(512, 4), 256, 0, stream>>>(x, Wv, Vt);
  k_flash<<<dim3(128, 8), 256, 0, stream>>>(Qh, Kh, Vt, lens, attn);
  k_gemm<<<dim3(512, 4), 256, 0, stream>>>(attn, Wt, t);   // t overlays Qh/Kh (dead)
  k_stats<<<256, 256, 0, stream>>>(t, mask, sums);
  k_final<<<8192, 256, 0, stream>>>(x, mask, t, gamma, beta, sums, lens, out);
}

// Round 3
// 511.385 us; speedup vs baseline: 4.1227x; 1.2264x over previous
//
#include <hip/hip_runtime.h>
#include <cmath>

typedef _Float16 f16;
typedef f16 f16x8 __attribute__((ext_vector_type(8)));
typedef f16 f16x4 __attribute__((ext_vector_type(4)));
typedef float f32x4 __attribute__((ext_vector_type(4)));

#define Ln 4096
#define Dn 256
#define NEGV (-1e30f)

// workspace byte offsets (~80.6MB; R0 proved >=100.6MB available)
#define B_XH   0ul           // fp16 x [8][4096][256] = 16MB (dead after k_qkv)
#define B_QH   (16ul << 20)  // fp16 Q = 16MB (dead after flash)
#define B_KH   (32ul << 20)  // fp16 K = 16MB (dead after flash)
#define B_VT   (48ul << 20)  // fp16 V^T [8][256][4096] = 16MB (dead after flash)
#define B_ATH  (64ul << 20)  // fp16 attn = 16MB
#define B_T    0ul           // fp32 t = 32MB, overlays XH+QH (dead by then)
#define B_LENS (80ul << 20)  // lens[8]
#define B_SUMS (B_LENS + 128)         // 512 floats
#define B_WQT  (B_LENS + 4096)        // fp16 WqT [256n][256k] = 128KB
#define B_WKT  (B_WQT + (128ul<<10))
#define B_WVT  (B_WKT + (128ul<<10))
#define B_WTT  (B_WVT + (128ul<<10))

__device__ __forceinline__ void async_ld16(f16* lds, const f16* g) {
  __builtin_amdgcn_global_load_lds((const __attribute__((address_space(1))) unsigned int*)g,
                                   (__attribute__((address_space(3))) unsigned int*)lds, 16, 0, 0);
}

__global__ __launch_bounds__(256) void k_init(const int* __restrict__ mask, int* __restrict__ lens,
                                              float* __restrict__ sums) {
  const int b = blockIdx.x, tid = threadIdx.x;
  if (b == 0) { sums[tid] = 0.f; sums[256 + tid] = 0.f; }
  int cnt = 0;
  for (int l = tid; l < Ln; l += 256) cnt += (mask[b * Ln + l] != 0) ? 1 : 0;
  __shared__ int red[256];
  red[tid] = cnt;
  __syncthreads();
  for (int s = 128; s > 0; s >>= 1) {
    if (tid < s) red[tid] += red[tid + s];
    __syncthreads();
  }
  if (tid == 0) lens[b] = red[0];
}

__global__ __launch_bounds__(256) void k_cast_x(const float* __restrict__ x, f16* __restrict__ xh) {
  const size_t i = ((size_t)blockIdx.x * 256 + threadIdx.x) * 4;
  float4 v = *(const float4*)&x[i];
  f16x4 h = {(f16)v.x, (f16)v.y, (f16)v.z, (f16)v.w};
  *(f16x4*)&xh[i] = h;
}

// transpose+cast one 64x64 tile of one weight matrix: WT[n][k] = (f16)W[k][n]
__global__ __launch_bounds__(256) void k_cast_w(const float* __restrict__ W0, const float* __restrict__ W1,
                                                const float* __restrict__ W2, const float* __restrict__ W3,
                                                f16* __restrict__ T0, f16* __restrict__ T1,
                                                f16* __restrict__ T2, f16* __restrict__ T3) {
  const float* Ws[4] = {W0, W1, W2, W3};
  f16* Ts[4] = {T0, T1, T2, T3};
  const float* W = Ws[blockIdx.x];
  f16* T = Ts[blockIdx.x];
  const int k0 = blockIdx.y * 64, n0 = blockIdx.z * 64;
  const int tid = threadIdx.x;
  __shared__ float ld[64][65];
#pragma unroll
  for (int i = 0; i < 16; ++i) {
    int flat = i * 256 + tid;
    int r = flat >> 6, c = flat & 63;
    ld[r][c] = W[(size_t)(k0 + r) * Dn + n0 + c];
  }
  __syncthreads();
#pragma unroll
  for (int i = 0; i < 16; ++i) {
    int flat = i * 256 + tid;
    int r = flat >> 6, c = flat & 63;
    T[(size_t)(n0 + r) * Dn + k0 + c] = (f16)ld[c][r];
  }
}

// Fused QKV projection: 64-row tile, 4 waves in 2x2 (row-half x col-half).
// A (xh) staged in LDS (swizzled global_load_lds); B frags direct from L2-resident W^T.
// Q,K row-major fp16; V written transposed (Vt[b][ch][l]) via LDS transpose tile.
__global__ __launch_bounds__(256) void k_qkv(const f16* __restrict__ xh, const f16* __restrict__ WqT,
                                             const f16* __restrict__ WkT, const f16* __restrict__ WvT,
                                             f16* __restrict__ Qh, f16* __restrict__ Kh,
                                             f16* __restrict__ Vt) {
  __shared__ f16 sA[64 * 256];   // 32KB
  __shared__ f16 vts[256 * 72];  // 36KB transpose tile (used only for V epilogue)
  const int tid = threadIdx.x;
  const int lane = tid & 63;
  const int ln15 = lane & 15;
  const int quad = lane >> 4;
  const int wave = tid >> 6;
  const int wr = wave >> 1;  // row half (32 rows)
  const int wn = wave & 1;   // col half (128 cols)
  const size_t row0 = (size_t)blockIdx.x * 64;

  {
    const f16* src = xh + row0 * Dn;
#pragma unroll
    for (int i = 0; i < 8; ++i) {
      int flat = i * 256 + tid;
      int r = flat >> 5, p = flat & 31;
      int g = p ^ (r & 7);
      async_ld16(&sA[(i * 256 + (tid & 192)) * 8], src + r * 256 + g * 8);
    }
  }
  __syncthreads();

  f16x8 af[2][8];
#pragma unroll
  for (int rg = 0; rg < 2; ++rg) {
    int r = wr * 32 + rg * 16 + ln15;
    int sw = r & 7;
#pragma unroll
    for (int c = 0; c < 8; ++c)
      af[rg][c] = *(const f16x8*)&sA[r * 256 + (((c * 4 + quad) ^ sw) << 3)];
  }

  const f16* Bm[3] = {WqT, WkT, WvT};
  for (int m = 0; m < 3; ++m) {
    const f16* B = Bm[m];
    f32x4 acc0[8], acc1[8];
#pragma unroll
    for (int nt = 0; nt < 8; ++nt) {
#pragma unroll
      for (int i = 0; i < 4; ++i) { acc0[nt][i] = 0.f; acc1[nt][i] = 0.f; }
    }
#pragma unroll
    for (int c = 0; c < 8; ++c) {
#pragma unroll
      for (int nt = 0; nt < 8; ++nt) {
        f16x8 bf = *(const f16x8*)&B[(size_t)(wn * 128 + nt * 16 + ln15) * 256 + c * 32 + quad * 8];
        acc0[nt] = __builtin_amdgcn_mfma_f32_16x16x32_f16(af[0][c], bf, acc0[nt], 0, 0, 0);
        acc1[nt] = __builtin_amdgcn_mfma_f32_16x16x32_f16(af[1][c], bf, acc1[nt], 0, 0, 0);
      }
    }
    if (m < 2) {
      f16* dst = (m == 0) ? Qh : Kh;
#pragma unroll
      for (int nt = 0; nt < 8; ++nt) {
        int col = wn * 128 + nt * 16 + ln15;
#pragma unroll
        for (int i = 0; i < 4; ++i) {
          dst[(row0 + wr * 32 + quad * 4 + i) * (size_t)Dn + col] = (f16)acc0[nt][i];
          dst[(row0 + wr * 32 + 16 + quad * 4 + i) * (size_t)Dn + col] = (f16)acc1[nt][i];
        }
      }
    } else {
#pragma unroll
      for (int nt = 0; nt < 8; ++nt) {
        int ch = wn * 128 + nt * 16 + ln15;
#pragma unroll
        for (int i = 0; i < 4; ++i) {
          vts[ch * 72 + wr * 32 + quad * 4 + i] = (f16)acc0[nt][i];
          vts[ch * 72 + wr * 32 + 16 + quad * 4 + i] = (f16)acc1[nt][i];
        }
      }
      __syncthreads();
      const int b = (int)(row0 >> 12);
      const int l0 = (int)(row0 & 4095);
      f16* vdst = Vt + (size_t)b * Dn * Ln + (size_t)tid * Ln + l0;
#pragma unroll
      for (int j = 0; j < 8; ++j)
        *(f16x8*)(vdst + 8 * j) = *(const f16x8*)&vts[tid * 72 + 8 * j];
    }
  }
}

// t = attn @ Wt : same structure, single matrix, fp32 output
__global__ __launch_bounds__(256) void k_t(const f16* __restrict__ ah, const f16* __restrict__ WtT,
                                           float* __restrict__ t) {
  __shared__ f16 sA[64 * 256];
  const int tid = threadIdx.x;
  const int lane = tid & 63;
  const int ln15 = lane & 15;
  const int quad = lane >> 4;
  const int wave = tid >> 6;
  const int wr = wave >> 1;
  const int wn = wave & 1;
  const size_t row0 = (size_t)blockIdx.x * 64;
  {
    const f16* src = ah + row0 * Dn;
#pragma unroll
    for (int i = 0; i < 8; ++i) {
      int flat = i * 256 + tid;
      int r = flat >> 5, p = flat & 31;
      int g = p ^ (r & 7);
      async_ld16(&sA[(i * 256 + (tid & 192)) * 8], src + r * 256 + g * 8);
    }
  }
  __syncthreads();
  f16x8 af[2][8];
#pragma unroll
  for (int rg = 0; rg < 2; ++rg) {
    int r = wr * 32 + rg * 16 + ln15;
    int sw = r & 7;
#pragma unroll
    for (int c = 0; c < 8; ++c)
      af[rg][c] = *(const f16x8*)&sA[r * 256 + (((c * 4 + quad) ^ sw) << 3)];
  }
  f32x4 acc0[8], acc1[8];
#pragma unroll
  for (int nt = 0; nt < 8; ++nt) {
#pragma unroll
    for (int i = 0; i < 4; ++i) { acc0[nt][i] = 0.f; acc1[nt][i] = 0.f; }
  }
#pragma unroll
  for (int c = 0; c < 8; ++c) {
#pragma unroll
    for (int nt = 0; nt < 8; ++nt) {
      f16x8 bf = *(const f16x8*)&WtT[(size_t)(wn * 128 + nt * 16 + ln15) * 256 + c * 32 + quad * 8];
      acc0[nt] = __builtin_amdgcn_mfma_f32_16x16x32_f16(af[0][c], bf, acc0[nt], 0, 0, 0);
      acc1[nt] = __builtin_amdgcn_mfma_f32_16x16x32_f16(af[1][c], bf, acc1[nt], 0, 0, 0);
    }
  }
#pragma unroll
  for (int nt = 0; nt < 8; ++nt) {
    int col = wn * 128 + nt * 16 + ln15;
#pragma unroll
    for (int i = 0; i < 4; ++i) {
      t[(row0 + wr * 32 + quad * 4 + i) * (size_t)Dn + col] = acc0[nt][i];
      t[(row0 + wr * 32 + 16 + quad * 4 + i) * (size_t)Dn + col] = acc1[nt][i];
    }
  }
}

// MFMA flash attention: 32 queries/block, 64-key tiles, 4 waves. (unchanged from R2 except fp16 out)
__global__ __launch_bounds__(256) void k_flash(const f16* __restrict__ Qh, const f16* __restrict__ Kh,
                                               const f16* __restrict__ Vt, const int* __restrict__ lens,
                                               f16* __restrict__ attn) {
  const int b = blockIdx.y;
  const int len = lens[b];
  const int i0 = blockIdx.x * 32;
  if (i0 >= len) return;
  const int tid = threadIdx.x;
  const int lane = tid & 63;
  const int ln15 = lane & 15;
  const int quad = lane >> 4;
  const int wave = tid >> 6;
  const int wq = wave >> 1;
  const int wk = wave & 1;

  __shared__ f16 sK[64 * 256];
  __shared__ f16 sV[256 * 64];
  __shared__ f16 sP[32 * 80];
  __shared__ float sRed[2][2][32];

  const f16* Qb = Qh + (size_t)b * Ln * Dn;
  const f16* Kb = Kh + (size_t)b * Ln * Dn;
  const f16* Vb = Vt + (size_t)b * Dn * Ln;
  f16* Ab = attn + (size_t)b * Ln * Dn;

  f16x8 qf[8];
  {
    const f16* qrow = Qb + (size_t)(i0 + wq * 16 + ln15) * Dn + quad * 8;
#pragma unroll
    for (int c = 0; c < 8; ++c) qf[c] = *(const f16x8*)(qrow + c * 32);
  }

  f32x4 oAcc[8];
#pragma unroll
  for (int nf = 0; nf < 8; ++nf) { oAcc[nf][0] = 0.f; oAcc[nf][1] = 0.f; oAcc[nf][2] = 0.f; oAcc[nf][3] = 0.f; }
  float m_i[4], l_i[4];
#pragma unroll
  for (int i = 0; i < 4; ++i) { m_i[i] = -INFINITY; l_i[i] = 0.f; }

  for (int j0 = 0; j0 < len; j0 += 64) {
    __syncthreads();
    {
      const f16* src = Kb + (size_t)j0 * Dn;
#pragma unroll
      for (int i = 0; i < 8; ++i) {
        int flat = i * 256 + tid;
        int r = flat >> 5, p = flat & 31;
        int g = p ^ (r & 7);
        async_ld16(&sK[(i * 256 + (tid & 192)) * 8], src + r * 256 + g * 8);
      }
      const f16* vsrc = Vb + j0;
#pragma unroll
      for (int i = 0; i < 8; ++i) {
        int flat = i * 256 + tid;
        int r = flat >> 3, p = flat & 7;
        int g = p ^ (r & 7);
        async_ld16(&sV[(i * 256 + (tid & 192)) * 8], vsrc + (size_t)r * Ln + g * 8);
      }
    }
    __syncthreads();

    f32x4 s0, s1;
    s0[0] = s0[1] = s0[2] = s0[3] = 0.f;
    s1[0] = s1[1] = s1[2] = s1[3] = 0.f;
    const int kr0 = wk * 32 + ln15;
    const int kr1 = kr0 + 16;
    const int sw = (kr0 & 7);
#pragma unroll
    for (int c = 0; c < 8; ++c) {
      int g = c * 4 + quad;
      f16x8 b0 = *(const f16x8*)&sK[kr0 * 256 + ((g ^ sw) << 3)];
      f16x8 b1 = *(const f16x8*)&sK[kr1 * 256 + ((g ^ sw) << 3)];
      s0 = __builtin_amdgcn_mfma_f32_16x16x32_f16(qf[c], b0, s0, 0, 0, 0);
      s1 = __builtin_amdgcn_mfma_f32_16x16x32_f16(qf[c], b1, s1, 0, 0, 0);
    }

    const int keyg = j0 + wk * 32 + ln15;
    const bool inv0 = keyg >= len, inv1 = keyg + 16 >= len;
    float rowmax[4], mnew[4], psum[4];
#pragma unroll
    for (int i = 0; i < 4; ++i) {
      float a = inv0 ? NEGV : s0[i];
      float c2 = inv1 ? NEGV : s1[i];
      s0[i] = a; s1[i] = c2;
      float rm = fmaxf(a, c2);
      rm = fmaxf(rm, __shfl_xor(rm, 1));
      rm = fmaxf(rm, __shfl_xor(rm, 2));
      rm = fmaxf(rm, __shfl_xor(rm, 4));
      rm = fmaxf(rm, __shfl_xor(rm, 8));
      rowmax[i] = rm;
    }
    if (ln15 == 0) {
#pragma unroll
      for (int i = 0; i < 4; ++i) sRed[0][wk][wq * 16 + quad * 4 + i] = rowmax[i];
    }
    __syncthreads();
#pragma unroll
    for (int i = 0; i < 4; ++i) {
      int row = wq * 16 + quad * 4 + i;
      float mo = fmaxf(sRed[0][0][row], sRed[0][1][row]);
      float mn = fmaxf(m_i[i], mo);
      mnew[i] = mn;
      float p0 = __expf(s0[i] - mn), p1 = __expf(s1[i] - mn);
      float rs = p0 + p1;
      rs += __shfl_xor(rs, 1);
      rs += __shfl_xor(rs, 2);
      rs += __shfl_xor(rs, 4);
      rs += __shfl_xor(rs, 8);
      psum[i] = rs;
      sP[row * 80 + wk * 32 + ln15] = (f16)p0;
      sP[row * 80 + wk * 32 + 16 + ln15] = (f16)p1;
    }
    if (ln15 == 0) {
#pragma unroll
      for (int i = 0; i < 4; ++i) sRed[1][wk][wq * 16 + quad * 4 + i] = psum[i];
    }
    __syncthreads();
    float alpha[4];
#pragma unroll
    for (int i = 0; i < 4; ++i) {
      int row = wq * 16 + quad * 4 + i;
      float tot = sRed[1][0][row] + sRed[1][1][row];
      float al = __expf(m_i[i] - mnew[i]);
      l_i[i] = l_i[i] * al + tot;
      m_i[i] = mnew[i];
      alpha[i] = al;
    }
#pragma unroll
    for (int nf = 0; nf < 8; ++nf) {
#pragma unroll
      for (int i = 0; i < 4; ++i) oAcc[nf][i] *= alpha[i];
    }
#pragma unroll
    for (int c = 0; c < 2; ++c) {
      f16x8 pa = *(const f16x8*)&sP[(wq * 16 + ln15) * 80 + c * 32 + quad * 8];
#pragma unroll
      for (int nf = 0; nf < 8; ++nf) {
        int ch = wk * 128 + nf * 16 + ln15;
        int g = c * 4 + quad;
        f16x8 vb2 = *(const f16x8*)&sV[ch * 64 + ((g ^ (ch & 7)) << 3)];
        oAcc[nf] = __builtin_amdgcn_mfma_f32_16x16x32_f16(pa, vb2, oAcc[nf], 0, 0, 0);
      }
    }
  }

#pragma unroll
  for (int i = 0; i < 4; ++i) {
    int row = i0 + wq * 16 + quad * 4 + i;
    if (row < len) {
      float inv = 1.f / l_i[i];
#pragma unroll
      for (int nf = 0; nf < 8; ++nf)
        Ab[(size_t)row * Dn + wk * 128 + nf * 16 + ln15] = (f16)(oAcc[nf][i] * inv);
    }
  }
}

__global__ __launch_bounds__(256) void k_stats(const float* __restrict__ t, const int* __restrict__ mask,
                                               float* __restrict__ sums) {
  const int c = threadIdx.x;
  const int r0 = blockIdx.x * 128;
  float s = 0.f, s2 = 0.f;
  for (int r = r0; r < r0 + 128; ++r) {
    if (mask[r] != 0) {
      float xv = t[(size_t)r * Dn + c];
      s += xv; s2 += xv * xv;
    }
  }
  atomicAdd(&sums[c], s);
  atomicAdd(&sums[256 + c], s2);
}

__device__ __forceinline__ float bn_relu(float tv, int ch, float fn, const float* sums,
                                         const float* gamma, const float* beta) {
  float mean = sums[ch] / fn;
  float var = sums[256 + ch] / fn - mean * mean;
  float y = gamma[ch] * (tv - mean) * rsqrtf(var + 1e-4f) + beta[ch];
  return y > 0.f ? y : 0.f;
}

__global__ __launch_bounds__(256) void k_final(const float* __restrict__ x, const int* __restrict__ mask,
                                               const float* __restrict__ t, const float* __restrict__ gamma,
                                               const float* __restrict__ beta, const float* __restrict__ sums,
                                               const int* __restrict__ lens, float* __restrict__ out) {
  const size_t idx = (size_t)blockIdx.x * 256 + threadIdx.x;
  const size_t row = idx >> 6;
  const int c = (int)(idx & 63) * 4;
  float4 o;
  if (mask[row] == 0) {
    o = make_float4(0.f, 0.f, 0.f, 0.f);
  } else {
    int n = 0;
#pragma unroll
    for (int i = 0; i < 8; ++i) n += lens[i];
    const float fn = (float)n;
    float4 tv = *(const float4*)&t[row * Dn + c];
    float4 xv = *(const float4*)&x[row * Dn + c];
    o.x = xv.x + bn_relu(tv.x, c + 0, fn, sums, gamma, beta);
    o.y = xv.y + bn_relu(tv.y, c + 1, fn, sums, gamma, beta);
    o.z = xv.z + bn_relu(tv.z, c + 2, fn, sums, gamma, beta);
    o.w = xv.w + bn_relu(tv.w, c + 3, fn, sums, gamma, beta);
  }
  *(float4*)&out[idx * 4] = o;
}

extern "C" void kernel_launch(void* const* d_in, const int* in_sizes, int n_in,
                              void* d_out, int out_size, void* d_ws, size_t ws_size,
                              hipStream_t stream) {
  const float* x = (const float*)d_in[0];
  const int* mask = (const int*)d_in[1];
  const float* Wq = (const float*)d_in[2];
  const float* Wk = (const float*)d_in[3];
  const float* Wv = (const float*)d_in[4];
  const float* Wt = (const float*)d_in[5];
  const float* gamma = (const float*)d_in[6];
  const float* beta = (const float*)d_in[7];
  float* out = (float*)d_out;
  char* wsb = (char*)d_ws;

  f16* xh = (f16*)(wsb + B_XH);
  f16* Qh = (f16*)(wsb + B_QH);
  f16* Kh = (f16*)(wsb + B_KH);
  f16* Vt = (f16*)(wsb + B_VT);
  f16* ath = (f16*)(wsb + B_ATH);
  float* t = (float*)(wsb + B_T);
  int* lens = (int*)(wsb + B_LENS);
  float* sums = (float*)(wsb + B_SUMS);
  f16* WqT = (f16*)(wsb + B_WQT);
  f16* WkT = (f16*)(wsb + B_WKT);
  f16* WvT = (f16*)(wsb + B_WVT);
  f16* WtT = (f16*)(wsb + B_WTT);

  k_init<<<8, 256, 0, stream>>>(mask, lens, sums);
  k_cast_x<<<8192, 256, 0, stream>>>(x, xh);
  k_cast_w<<<dim3(4, 4, 4), 256, 0, stream>>>(Wq, Wk, Wv, Wt, WqT, WkT, WvT, WtT);
  k_qkv<<<512, 256, 0, stream>>>(xh, WqT, WkT, WvT, Qh, Kh, Vt);
  k_flash<<<dim3(128, 8), 256, 0, stream>>>(Qh, Kh, Vt, lens, ath);
  k_t<<<512, 256, 0, stream>>>(ath, WtT, t);  // t overlays xh/Qh (dead)
  k_stats<<<256, 256, 0, stream>>>(t, mask, sums);
  k_final<<<8192, 256, 0, stream>>>(x, mask, t, gamma, beta, sums, lens, out);
}